// Round 5
// baseline (2091.844 us; speedup 1.0000x reference)
//
#include <hip/hip_runtime.h>
#include <hip/hip_bf16.h>
#include <hip/hip_fp16.h>
#include <math.h>

#define UNITS 64
#define DEPTH_EMB 12
#define DEPTH_PAR 5
#define GN_EPS 1e-5f

// ---------------- CSR build ----------------

__global__ void k_deg(const int* __restrict__ dst, int* __restrict__ cnt, int E) {
    int e = blockIdx.x * blockDim.x + threadIdx.x;
    if (e < E) atomicAdd(&cnt[dst[e]], 1);
}

__global__ void k_dinv(const int* __restrict__ cnt, float* __restrict__ dinv, int n) {
    int i = blockIdx.x * blockDim.x + threadIdx.x;
    if (i < n) dinv[i] = rsqrtf(1.0f + (float)cnt[i]);
}

__global__ void k_chunksum(const int* __restrict__ cnt, int* __restrict__ csum, int n) {
    __shared__ int sd[256];
    int base = blockIdx.x * 1024;
    int s = 0;
    for (int i = threadIdx.x; i < 1024; i += 256) {
        int idx = base + i;
        if (idx < n) s += cnt[idx];
    }
    sd[threadIdx.x] = s;
    __syncthreads();
    for (int off = 128; off > 0; off >>= 1) {
        if (threadIdx.x < off) sd[threadIdx.x] += sd[threadIdx.x + off];
        __syncthreads();
    }
    if (threadIdx.x == 0) csum[blockIdx.x] = sd[0];
}

__global__ void k_scansum(const int* __restrict__ csum, int* __restrict__ coff,
                          int* __restrict__ rowptr, int nchunks) {
    __shared__ int sd[256];
    int tid = threadIdx.x;
    int v = (tid < nchunks) ? csum[tid] : 0;
    sd[tid] = v;
    __syncthreads();
    for (int off = 1; off < 256; off <<= 1) {
        int t = (tid >= off) ? sd[tid - off] : 0;
        __syncthreads();
        sd[tid] += t;
        __syncthreads();
    }
    if (tid < nchunks) coff[tid] = sd[tid] - v;
    if (tid == 0) rowptr[0] = 0;
}

__global__ void k_scanfinal(const int* __restrict__ cnt, const int* __restrict__ coff,
                            int* __restrict__ rowptr, int n) {
    __shared__ int sd[1024];
    int base = blockIdx.x * 1024;
    int tid = threadIdx.x;
    int idx = base + tid;
    int v = (idx < n) ? cnt[idx] : 0;
    sd[tid] = v;
    __syncthreads();
    for (int off = 1; off < 1024; off <<= 1) {
        int t = (tid >= off) ? sd[tid - off] : 0;
        __syncthreads();
        sd[tid] += t;
        __syncthreads();
    }
    if (idx < n) rowptr[idx + 1] = coff[blockIdx.x] + sd[tid];
}

__global__ void k_fill(const int* __restrict__ src, const int* __restrict__ dst,
                       const int* __restrict__ rowptr, int* __restrict__ fill,
                       int* __restrict__ srcs, int E) {
    int e = blockIdx.x * blockDim.x + threadIdx.x;
    if (e >= E) return;
    int s = src[e], d = dst[e];
    int p = rowptr[d] + atomicAdd(&fill[d], 1);
    srcs[p] = s;
}

// ---------------- layer 0: h2 = f16(dinv * (x @ w0)) ----------------

__global__ void k_l0(const float* __restrict__ x, const float* __restrict__ w0,
                     const float* __restrict__ dinv, __half* __restrict__ h2, int n) {
    int gid = blockIdx.x * blockDim.x + threadIdx.x;
    if (gid >= n * UNITS) return;
    int node = gid >> 6, c = gid & 63;
    h2[gid] = __float2half(x[node] * w0[c] * dinv[node]);
}

// ---------------- dual-stream gather ----------------
// h[d] = dinv[d]*(sum_{s in adj(d)} h2[s] + h2[d]) + b ; optional stats

#define GBATCH8(hsrc, J, A0, A1, A2, A3)                                   \
    {                                                                      \
        int i0 = srcs[J + 0], i1 = srcs[J + 1], i2 = srcs[J + 2],          \
            i3 = srcs[J + 3], i4 = srcs[J + 4], i5 = srcs[J + 5],          \
            i6 = srcs[J + 6], i7 = srcs[J + 7];                            \
        float v0 = __half2float(hsrc[(size_t)i0 * UNITS + lane]);          \
        float v1 = __half2float(hsrc[(size_t)i1 * UNITS + lane]);          \
        float v2 = __half2float(hsrc[(size_t)i2 * UNITS + lane]);          \
        float v3 = __half2float(hsrc[(size_t)i3 * UNITS + lane]);          \
        float v4 = __half2float(hsrc[(size_t)i4 * UNITS + lane]);          \
        float v5 = __half2float(hsrc[(size_t)i5 * UNITS + lane]);          \
        float v6 = __half2float(hsrc[(size_t)i6 * UNITS + lane]);          \
        float v7 = __half2float(hsrc[(size_t)i7 * UNITS + lane]);          \
        A0 += v0; A1 += v1; A2 += v2; A3 += v3;                            \
        A0 += v4; A1 += v5; A2 += v6; A3 += v7;                            \
    }

template <int DO_STATS>
__global__ void k_gather(const __half* __restrict__ h2, float* __restrict__ h,
                         const int* __restrict__ rowptr, const int* __restrict__ srcs,
                         const float* __restrict__ dinv, const float* __restrict__ b,
                         float* __restrict__ stats, int n, int half) {
    int lane = threadIdx.x & 63;
    int wib = threadIdx.x >> 6;
    int wpb = blockDim.x >> 6;
    int gwave = blockIdx.x * wpb + wib;
    int nwaves = gridDim.x * wpb;
    float bj = b[lane];
    float s1 = 0.0f, s2 = 0.0f;

    for (int nd = gwave; nd < half; nd += nwaves) {
        int nodeA = __builtin_amdgcn_readfirstlane(nd);
        int nodeB = nodeA + half;
        bool hasB = nodeB < n;

        int jA = rowptr[nodeA], endA = rowptr[nodeA + 1];
        int jB = 0, endB = 0;
        if (hasB) { jB = rowptr[nodeB]; endB = rowptr[nodeB + 1]; }

        float aA0 = __half2float(h2[(size_t)nodeA * UNITS + lane]);
        float aA1 = 0.0f, aA2 = 0.0f, aA3 = 0.0f;
        float aB0 = hasB ? __half2float(h2[(size_t)nodeB * UNITS + lane]) : 0.0f;
        float aB1 = 0.0f, aB2 = 0.0f, aB3 = 0.0f;

        // interleaved 8-batches: issue A loads, issue B loads, then consume
        bool dA = jA + 8 <= endA, dB = jB + 8 <= endB;
        while (dA || dB) {
            float vA[8], vB[8];
            if (dA) {
                int i0 = srcs[jA + 0], i1 = srcs[jA + 1], i2 = srcs[jA + 2], i3 = srcs[jA + 3];
                int i4 = srcs[jA + 4], i5 = srcs[jA + 5], i6 = srcs[jA + 6], i7 = srcs[jA + 7];
                vA[0] = __half2float(h2[(size_t)i0 * UNITS + lane]);
                vA[1] = __half2float(h2[(size_t)i1 * UNITS + lane]);
                vA[2] = __half2float(h2[(size_t)i2 * UNITS + lane]);
                vA[3] = __half2float(h2[(size_t)i3 * UNITS + lane]);
                vA[4] = __half2float(h2[(size_t)i4 * UNITS + lane]);
                vA[5] = __half2float(h2[(size_t)i5 * UNITS + lane]);
                vA[6] = __half2float(h2[(size_t)i6 * UNITS + lane]);
                vA[7] = __half2float(h2[(size_t)i7 * UNITS + lane]);
            }
            if (dB) {
                int i0 = srcs[jB + 0], i1 = srcs[jB + 1], i2 = srcs[jB + 2], i3 = srcs[jB + 3];
                int i4 = srcs[jB + 4], i5 = srcs[jB + 5], i6 = srcs[jB + 6], i7 = srcs[jB + 7];
                vB[0] = __half2float(h2[(size_t)i0 * UNITS + lane]);
                vB[1] = __half2float(h2[(size_t)i1 * UNITS + lane]);
                vB[2] = __half2float(h2[(size_t)i2 * UNITS + lane]);
                vB[3] = __half2float(h2[(size_t)i3 * UNITS + lane]);
                vB[4] = __half2float(h2[(size_t)i4 * UNITS + lane]);
                vB[5] = __half2float(h2[(size_t)i5 * UNITS + lane]);
                vB[6] = __half2float(h2[(size_t)i6 * UNITS + lane]);
                vB[7] = __half2float(h2[(size_t)i7 * UNITS + lane]);
            }
            if (dA) {
                aA0 += vA[0]; aA1 += vA[1]; aA2 += vA[2]; aA3 += vA[3];
                aA0 += vA[4]; aA1 += vA[5]; aA2 += vA[6]; aA3 += vA[7];
                jA += 8;
            }
            if (dB) {
                aB0 += vB[0]; aB1 += vB[1]; aB2 += vB[2]; aB3 += vB[3];
                aB0 += vB[4]; aB1 += vB[5]; aB2 += vB[6]; aB3 += vB[7];
                jB += 8;
            }
            dA = jA + 8 <= endA;
            dB = jB + 8 <= endB;
        }
        // tails
        for (; jA + 4 <= endA; jA += 4) {
            int i0 = srcs[jA + 0], i1 = srcs[jA + 1], i2 = srcs[jA + 2], i3 = srcs[jA + 3];
            aA0 += __half2float(h2[(size_t)i0 * UNITS + lane]);
            aA1 += __half2float(h2[(size_t)i1 * UNITS + lane]);
            aA2 += __half2float(h2[(size_t)i2 * UNITS + lane]);
            aA3 += __half2float(h2[(size_t)i3 * UNITS + lane]);
        }
        for (; jA < endA; ++jA) aA0 += __half2float(h2[(size_t)srcs[jA] * UNITS + lane]);
        float accA = (aA0 + aA1) + (aA2 + aA3);
        float hvA = fmaf(accA, dinv[nodeA], bj);
        h[(size_t)nodeA * UNITS + lane] = hvA;
        if (DO_STATS) { s1 += hvA; s2 = fmaf(hvA, hvA, s2); }

        if (hasB) {
            for (; jB + 4 <= endB; jB += 4) {
                int i0 = srcs[jB + 0], i1 = srcs[jB + 1], i2 = srcs[jB + 2], i3 = srcs[jB + 3];
                aB0 += __half2float(h2[(size_t)i0 * UNITS + lane]);
                aB1 += __half2float(h2[(size_t)i1 * UNITS + lane]);
                aB2 += __half2float(h2[(size_t)i2 * UNITS + lane]);
                aB3 += __half2float(h2[(size_t)i3 * UNITS + lane]);
            }
            for (; jB < endB; ++jB) aB0 += __half2float(h2[(size_t)srcs[jB] * UNITS + lane]);
            float accB = (aB0 + aB1) + (aB2 + aB3);
            float hvB = fmaf(accB, dinv[nodeB], bj);
            h[(size_t)nodeB * UNITS + lane] = hvB;
            if (DO_STATS) { s1 += hvB; s2 = fmaf(hvB, hvB, s2); }
        }
    }

    if (DO_STATS) {
        __shared__ float sd[2][4][UNITS];
        sd[0][wib][lane] = s1;
        sd[1][wib][lane] = s2;
        __syncthreads();
        if (threadIdx.x < UNITS) {
            float a1 = 0.0f, a2 = 0.0f;
            for (int r = 0; r < wpb; ++r) {
                a1 += sd[0][r][lane];
                a2 += sd[1][r][lane];
            }
            atomicAdd(&stats[lane], a1);
            atomicAdd(&stats[UNITS + lane], a2);
        }
    }
}

// ---------------- fused GraphNorm + SiLU + linear (embedding) ----------------
// out_h2 = f16( dinv[node] * ( silu(gn(in[node])) @ W ) )

__global__ void k_linear_nsf(const float* __restrict__ in, __half* __restrict__ out,
                             const float* __restrict__ W, const float* __restrict__ dinv,
                             const float* __restrict__ stats, const float* __restrict__ gamma,
                             const float* __restrict__ beta, const float* __restrict__ alpha,
                             float inv_n, int n) {
    int lane = threadIdx.x & 63;
    int wib = threadIdx.x >> 6;
    int wpb = blockDim.x >> 6;
    int gwave = blockIdx.x * wpb + wib;
    int nwaves = gridDim.x * wpb;

    float w[UNITS];
#pragma unroll
    for (int k = 0; k < UNITS; ++k) w[k] = W[k * UNITS + lane];

    // per-lane GraphNorm affine (feature = lane)
    float m = stats[lane] * inv_n;
    float ex2 = stats[UNITS + lane] * inv_n;
    float al = alpha[lane];
    float var = ex2 - m * m * (2.0f * al - al * al);
    float g = gamma[lane] * rsqrtf(var + GN_EPS);
    float A = g;
    float Bc = beta[lane] - g * al * m;

    for (int nd = gwave; nd < n; nd += nwaves) {
        int node = __builtin_amdgcn_readfirstlane(nd);
        float hv = in[(size_t)node * UNITS + lane];      // coalesced
        float t = fmaf(hv, A, Bc);
        t = t / (1.0f + __expf(-t));                      // silu, per-lane
        float di = dinv[node];
        float a0 = 0.0f, a1 = 0.0f, a2 = 0.0f, a3 = 0.0f;
#pragma unroll
        for (int k = 0; k < UNITS; k += 4) {
            a0 = fmaf(__shfl(t, k + 0, 64), w[k + 0], a0);
            a1 = fmaf(__shfl(t, k + 1, 64), w[k + 1], a1);
            a2 = fmaf(__shfl(t, k + 2, 64), w[k + 2], a2);
            a3 = fmaf(__shfl(t, k + 3, 64), w[k + 3], a3);
        }
        float acc = (a0 + a1) + (a2 + a3);
        out[(size_t)node * UNITS + lane] = __float2half(acc * di);
    }
}

// ---------------- ParNet linear: out = relu(in + in @ W + b) ----------------

__global__ void k_linear_par(const float* __restrict__ in, float* __restrict__ out,
                             const float* __restrict__ W, const float* __restrict__ b, int n) {
    int lane = threadIdx.x & 63;
    int wib = threadIdx.x >> 6;
    int wpb = blockDim.x >> 6;
    int gwave = blockIdx.x * wpb + wib;
    int nwaves = gridDim.x * wpb;

    float w[UNITS];
#pragma unroll
    for (int k = 0; k < UNITS; ++k) w[k] = W[k * UNITS + lane];
    float bj = b[lane];

    for (int nd = gwave; nd < n; nd += nwaves) {
        int node = __builtin_amdgcn_readfirstlane(nd);
        const float* __restrict__ row = in + (size_t)node * UNITS;
        float a0 = 0.0f, a1 = 0.0f, a2 = 0.0f, a3 = 0.0f;
#pragma unroll
        for (int k = 0; k < UNITS; k += 4) {
            a0 = fmaf(row[k + 0], w[k + 0], a0);
            a1 = fmaf(row[k + 1], w[k + 1], a1);
            a2 = fmaf(row[k + 2], w[k + 2], a2);
            a3 = fmaf(row[k + 3], w[k + 3], a3);
        }
        float acc = (a0 + a1) + (a2 + a3) + row[lane] + bj;
        acc = fmaxf(acc, 0.0f);
        out[(size_t)node * UNITS + lane] = acc;
    }
}

// ---------------- ParNet final linear + head fused ----------------
// acc = relu(in + in@W + b); out[node] = sigmoid(dot(acc, wl) + bl)

__global__ void k_linear_head(const float* __restrict__ in, const float* __restrict__ W,
                              const float* __restrict__ b, const float* __restrict__ wl,
                              const float* __restrict__ bl, float* __restrict__ out, int n) {
    int lane = threadIdx.x & 63;
    int wib = threadIdx.x >> 6;
    int wpb = blockDim.x >> 6;
    int gwave = blockIdx.x * wpb + wib;
    int nwaves = gridDim.x * wpb;

    float w[UNITS];
#pragma unroll
    for (int k = 0; k < UNITS; ++k) w[k] = W[k * UNITS + lane];
    float bj = b[lane];
    float wv = wl[lane];
    float blv = bl[0];

    for (int nd = gwave; nd < n; nd += nwaves) {
        int node = __builtin_amdgcn_readfirstlane(nd);
        const float* __restrict__ row = in + (size_t)node * UNITS;
        float a0 = 0.0f, a1 = 0.0f, a2 = 0.0f, a3 = 0.0f;
#pragma unroll
        for (int k = 0; k < UNITS; k += 4) {
            a0 = fmaf(row[k + 0], w[k + 0], a0);
            a1 = fmaf(row[k + 1], w[k + 1], a1);
            a2 = fmaf(row[k + 2], w[k + 2], a2);
            a3 = fmaf(row[k + 3], w[k + 3], a3);
        }
        float acc = (a0 + a1) + (a2 + a3) + row[lane] + bj;
        acc = fmaxf(acc, 0.0f);
        float p = acc * wv;
#pragma unroll
        for (int off = 32; off > 0; off >>= 1) p += __shfl_xor(p, off, 64);
        if (lane == 0) out[node] = 1.0f / (1.0f + __expf(-(p + blv)));
    }
}

// ---------------- host launch ----------------

extern "C" void kernel_launch(void* const* d_in, const int* in_sizes, int n_in,
                              void* d_out, int out_size, void* d_ws, size_t ws_size,
                              hipStream_t stream) {
    const float* x = (const float*)d_in[0];
    const int* ei = (const int*)d_in[1];
    const float* conv_w0 = (const float*)d_in[2];
    const float* conv_w = (const float*)d_in[3];
    const float* conv_b = (const float*)d_in[4];
    const float* gn_gamma = (const float*)d_in[5];
    const float* gn_beta = (const float*)d_in[6];
    const float* gn_alpha = (const float*)d_in[7];
    const float* phe_w = (const float*)d_in[8];
    const float* phe_b = (const float*)d_in[9];
    const float* phe_wl = (const float*)d_in[10];
    const float* phe_bl = (const float*)d_in[11];
    const float* heu_w = (const float*)d_in[12];
    const float* heu_b = (const float*)d_in[13];
    const float* heu_wl = (const float*)d_in[14];
    const float* heu_bl = (const float*)d_in[15];

    const int N = in_sizes[0];
    const int E = in_sizes[1] / 2;
    const int NC = N * UNITS;
    const int NCHUNK = (N + 1023) / 1024;
    const int HALF = (N + 1) / 2;

    const int* src = ei;
    const int* dstp = ei + E;

    char* w = (char*)d_ws;
    float* dinv = (float*)w;  w += (size_t)N * 4;
    float* h = (float*)w;     w += (size_t)NC * 4;
    float* hx = (float*)w;    w += (size_t)NC * 4;   // f16 h2 during embedding; fp32 parnet buffer
    float* h3 = (float*)w;    w += (size_t)NC * 4;
    float* stats = (float*)w; w += (size_t)DEPTH_EMB * 128 * 4;
    int* cnt = (int*)w;       w += (size_t)N * 4;
    int* rowptr = (int*)w;    w += (size_t)(N + 1) * 4;
    int* fillc = (int*)w;     w += (size_t)N * 4;
    int* srcs = (int*)w;      w += (size_t)E * 4;
    int* csum = (int*)w;      w += 256 * 4;
    int* coff = (int*)w;      w += 256 * 4;

    __half* h2 = (__half*)hx;
    float* out = (float*)d_out;

    const int B = 256;
    const int gE = (E + B - 1) / B;
    const int gN = (N + B - 1) / B;
    const int gNC = (NC + B - 1) / B;

    // ---- CSR build ----
    hipMemsetAsync(cnt, 0, (size_t)N * 4, stream);
    hipMemsetAsync(fillc, 0, (size_t)N * 4, stream);
    hipMemsetAsync(stats, 0, (size_t)DEPTH_EMB * 128 * 4, stream);
    k_deg<<<gE, B, 0, stream>>>(dstp, cnt, E);
    k_dinv<<<gN, B, 0, stream>>>(cnt, dinv, N);
    k_chunksum<<<NCHUNK, 256, 0, stream>>>(cnt, csum, N);
    k_scansum<<<1, 256, 0, stream>>>(csum, coff, rowptr, NCHUNK);
    k_scanfinal<<<NCHUNK, 1024, 0, stream>>>(cnt, coff, rowptr, N);
    k_fill<<<gE, B, 0, stream>>>(src, dstp, rowptr, fillc, srcs, E);

    // ---- GCN embedding ----
    k_l0<<<gNC, B, 0, stream>>>(x, conv_w0, dinv, h2, N);
    for (int i = 0; i < DEPTH_EMB; ++i) {
        float* st = stats + (size_t)i * 128;
        if (i < DEPTH_EMB - 1) {
            k_gather<1><<<2048, B, 0, stream>>>(h2, h, rowptr, srcs, dinv,
                                                conv_b + (size_t)i * UNITS, st, N, HALF);
            k_linear_nsf<<<2048, B, 0, stream>>>(h, h2, conv_w + (size_t)i * UNITS * UNITS,
                                                 dinv, st,
                                                 gn_gamma + (size_t)i * UNITS,
                                                 gn_beta + (size_t)i * UNITS,
                                                 gn_alpha + (size_t)i * UNITS,
                                                 1.0f / (float)N, N);
        } else {
            k_gather<0><<<2048, B, 0, stream>>>(h2, h, rowptr, srcs, dinv,
                                                conv_b + (size_t)i * UNITS, st, N, HALF);
        }
    }

    // ---- ParNet heads (h preserved; scratch h3/hx) ----
    for (int head = 0; head < 2; ++head) {
        const float* wsrc = head == 0 ? phe_w : heu_w;
        const float* bsrc = head == 0 ? phe_b : heu_b;
        const float* wl = head == 0 ? phe_wl : heu_wl;
        const float* bl = head == 0 ? phe_bl : heu_bl;
        float* o = out + (size_t)head * N;

        k_linear_par<<<2048, B, 0, stream>>>(h, h3, wsrc, bsrc, N);
        k_linear_par<<<2048, B, 0, stream>>>(h3, hx, wsrc + (size_t)1 * UNITS * UNITS,
                                             bsrc + (size_t)1 * UNITS, N);
        k_linear_par<<<2048, B, 0, stream>>>(hx, h3, wsrc + (size_t)2 * UNITS * UNITS,
                                             bsrc + (size_t)2 * UNITS, N);
        k_linear_head<<<2048, B, 0, stream>>>(h3, wsrc + (size_t)3 * UNITS * UNITS,
                                              bsrc + (size_t)3 * UNITS, wl, bl, o, N);
    }
}